// Round 5
// baseline (467.528 us; speedup 1.0000x reference)
//
#include <hip/hip_runtime.h>

typedef unsigned short u16;
typedef unsigned int u32;
typedef __attribute__((ext_vector_type(4))) float f32x4;
typedef __attribute__((ext_vector_type(8))) short bf16x8;   // 8 bf16 bit-patterns (4 VGPRs)
typedef __attribute__((ext_vector_type(8))) u16 u16x8;
typedef __attribute__((ext_vector_type(4))) u16 u16x4;
typedef __attribute__((ext_vector_type(4))) u32 u32x4;

#define GLOB_AS __attribute__((address_space(1)))
#define LDS_AS  __attribute__((address_space(3)))

__device__ __forceinline__ void gload_lds16(const void* g, void* l) {
  // async global->LDS, 16B per lane, LDS dest = wave-uniform base + lane*16
  __builtin_amdgcn_global_load_lds((const GLOB_AS void*)g, (LDS_AS void*)l, 16, 0, 0);
}

__device__ __forceinline__ u16 f2bf(float f) {  // RNE float->bf16
  u32 u = __builtin_bit_cast(u32, f);
  u += 0x7fffu + ((u >> 16) & 1u);
  return (u16)(u >> 16);
}

__device__ __forceinline__ float bf2f(u16 b) {
  u32 u = (u32)b << 16;
  return __builtin_bit_cast(float, u);
}

#define MFMA16(a, b, c) __builtin_amdgcn_mfma_f32_16x16x32_bf16(a, b, c, 0, 0, 0)

// ---------------- elementwise cast f32 -> bf16 ----------------
__global__ __launch_bounds__(256) void cast_f32_bf16(const float* __restrict__ s,
                                                     u16* __restrict__ d, int n8) {
  int i = blockIdx.x * 256 + threadIdx.x;
  if (i >= n8) return;
  const f32x4* sp = (const f32x4*)s;
  f32x4 a = sp[2 * i], b = sp[2 * i + 1];
  u16x8 o;
  o[0] = f2bf(a[0]); o[1] = f2bf(a[1]); o[2] = f2bf(a[2]); o[3] = f2bf(a[3]);
  o[4] = f2bf(b[0]); o[5] = f2bf(b[1]); o[6] = f2bf(b[2]); o[7] = f2bf(b[3]);
  ((u16x8*)d)[i] = o;
}

// ---------------- NT GEMM: C[m][n] = sum_k A[m][k]*B[n][k] + bias[n] ----------------
template <int OUTM>  // 0: f32 out, 1: bf16 out
__global__ __launch_bounds__(256) void gemm_nt(const u16* __restrict__ A,
                                               const u16* __restrict__ B,
                                               const float* __restrict__ bias,
                                               void* __restrict__ C) {
  constexpr int K = 2048, N = 2048;
  __shared__ u16 As[128 * 64];
  __shared__ u16 Bs[128 * 64];
  const int tid = threadIdx.x;
  const int wave = tid >> 6, lane = tid & 63;
  const int lg = lane >> 4, li = lane & 15;
  const int m0 = blockIdx.x * 128, n0 = blockIdx.y * 128;
  const int wr = (wave >> 1) * 64, wc = (wave & 1) * 64;

  const u16* Ag = A + (size_t)(m0 + 32 * wave + (lane >> 3)) * K + (lane & 7) * 8;
  const u16* Bg = B + (size_t)(n0 + 32 * wave + (lane >> 3)) * K + (lane & 7) * 8;
  u16* AsW = As + wave * 2048;
  u16* BsW = Bs + wave * 2048;

  f32x4 acc[4][4] = {};
  for (int k0 = 0; k0 < K; k0 += 64) {
    __syncthreads();
#pragma unroll
    for (int j = 0; j < 4; ++j) {
      gload_lds16(Ag + k0 + (size_t)(8 * j) * K, AsW + j * 512);
      gload_lds16(Bg + k0 + (size_t)(8 * j) * K, BsW + j * 512);
    }
    __syncthreads();
#pragma unroll
    for (int kk = 0; kk < 64; kk += 32) {
      bf16x8 af[4], bfr[4];
#pragma unroll
      for (int mi = 0; mi < 4; mi++)
        af[mi] = *(const bf16x8*)&As[(wr + mi * 16 + li) * 64 + kk + lg * 8];
#pragma unroll
      for (int ni = 0; ni < 4; ni++)
        bfr[ni] = *(const bf16x8*)&Bs[(wc + ni * 16 + li) * 64 + kk + lg * 8];
#pragma unroll
      for (int mi = 0; mi < 4; mi++)
#pragma unroll
        for (int ni = 0; ni < 4; ni++)
          acc[mi][ni] = MFMA16(af[mi], bfr[ni], acc[mi][ni]);
    }
  }
  float bcol[4];
#pragma unroll
  for (int ni = 0; ni < 4; ni++) bcol[ni] = bias[n0 + wc + ni * 16 + li];
#pragma unroll
  for (int mi = 0; mi < 4; mi++) {
#pragma unroll
    for (int ni = 0; ni < 4; ni++) {
      const int gm = m0 + wr + mi * 16 + lg * 4;
      const int gn = n0 + wc + ni * 16 + li;
#pragma unroll
      for (int r = 0; r < 4; r++) {
        float v = acc[mi][ni][r] + bcol[ni];
        if constexpr (OUTM == 0)
          ((float*)C)[(size_t)(gm + r) * N + gn] = v;
        else
          ((u16*)C)[(size_t)(gm + r) * N + gn] = f2bf(v);
      }
    }
  }
}

// ---------------- fused RMSNorm (over 2048) + 3-axis RoPE, f32 -> bf16 ----------------
__global__ __launch_bounds__(256) void rms_rope(const float* __restrict__ pre,
                                                const float* __restrict__ w,
                                                const float* __restrict__ fcos,
                                                const float* __restrict__ fsin,
                                                u16* __restrict__ out, float fold) {
  const int l = blockIdx.x, tid = threadIdx.x;
  const float* row = pre + (size_t)l * 2048;
  const int d0 = tid * 8;
  f32x4 v0 = *(const f32x4*)(row + d0);
  f32x4 v1 = *(const f32x4*)(row + d0 + 4);
  float ss = v0[0] * v0[0] + v0[1] * v0[1] + v0[2] * v0[2] + v0[3] * v0[3] +
             v1[0] * v1[0] + v1[1] * v1[1] + v1[2] * v1[2] + v1[3] * v1[3];
#pragma unroll
  for (int m = 32; m; m >>= 1) ss += __shfl_xor(ss, m);
  __shared__ float red[4];
  if ((tid & 63) == 0) red[tid >> 6] = ss;
  __syncthreads();
  const float scale =
      rsqrtf((red[0] + red[1] + red[2] + red[3]) * (1.0f / 2048.0f) + 1e-6f) * fold;
  f32x4 w0 = *(const f32x4*)(w + d0);
  f32x4 w1 = *(const f32x4*)(w + d0 + 4);
  float xs[8];
#pragma unroll
  for (int j = 0; j < 4; j++) {
    xs[j] = v0[j] * w0[j] * scale;
    xs[4 + j] = v1[j] * w1[j] * scale;
  }
  const int f = l / 640, rem = l % 640;
  const int hh = rem >> 5, ww = rem & 31;
  const int cb = (d0 & 127) >> 1;
  u16x8 ov;
#pragma unroll
  for (int i = 0; i < 4; i++) {
    const int c = cb + i;
    const int prow = c < 22 ? f : (c < 43 ? hh : ww);  // S0=22, S0+S1=43
    const float fc = fcos[prow * 64 + c];
    const float fs = fsin[prow * 64 + c];
    const float xr = xs[2 * i], xi = xs[2 * i + 1];
    ov[2 * i] = f2bf(xr * fc - xi * fs);
    ov[2 * i + 1] = f2bf(xr * fs + xi * fc);
  }
  *(u16x8*)(out + (size_t)l * 2048 + d0) = ov;
}

// ---------------- bf16 transpose [3200][2048] -> [2048][3200] ----------------
__global__ __launch_bounds__(256) void transpose_2d(const u16* __restrict__ src,
                                                    u16* __restrict__ dst) {
  __shared__ u16 t[64][72];
  const int m0 = blockIdx.x * 64, n0 = blockIdx.y * 64;
  const int tid = threadIdx.x;
  const int r = tid >> 3, c8 = (tid & 7) * 8;
#pragma unroll
  for (int j = 0; j < 2; j++) {
    u16x8 v = *(const u16x8*)&src[(size_t)(m0 + r + 32 * j) * 2048 + n0 + c8];
#pragma unroll
    for (int e = 0; e < 8; e++) t[c8 + e][r + 32 * j] = v[e];
  }
  __syncthreads();
#pragma unroll
  for (int j = 0; j < 2; j++) {
    u16x8 v = *(const u16x8*)&t[r + 32 * j][c8];
    *(u16x8*)&dst[(size_t)(n0 + r + 32 * j) * 3200 + m0 + c8] = v;
  }
}

// ---------------- flash attention, KV-split x2, double-buffered LDS K/V ----------------
// Swapped QK^T (mfma(K,Q) -> S^T): each lane owns q=li, kv = lg*4+{0..3} and 16+lg*4+{0..3}.
// Softmax fully in-register (scalar m,l per lane); P packed via v_cvt_pk_bf16_f32; PV reads
// V^T as two 8B granules per f8 (k-slot permutation absorbed into the V read pattern).
__global__ __launch_bounds__(256) void attn_kernel(const u16* __restrict__ Q,
                                                   const u16* __restrict__ Kb,
                                                   const u16* __restrict__ VT,
                                                   u16* __restrict__ Opart,
                                                   float* __restrict__ ml) {
  __shared__ u16 Klds[2][32 * 128];
  __shared__ u16 Vlds[2][128 * 32];
  const int tid = threadIdx.x, wave = tid >> 6, lane = tid & 63;
  const int lg = lane >> 4, li = lane & 15;

  // bijective XCD-aware remap: lid = x + 50y + 800z; xcd = lid&7 -> heads {2x,2x+1}
  const int lid = blockIdx.x + 50 * blockIdx.y + 800 * blockIdx.z;
  const int xcd = lid & 7, ixd = lid >> 3;
  const int h = xcd * 2 + (ixd & 1);
  const int rem = ixd >> 1;
  const int split = rem & 1;
  const int qrow0 = (rem >> 1) * 64 + wave * 16;
  const int n0base = split * 1600;

  bf16x8 qf[4];
  {
    const u16* qb = Q + (size_t)(qrow0 + li) * 2048 + h * 128 + lg * 8;
#pragma unroll
    for (int ks = 0; ks < 4; ks++) qf[ks] = *(const bf16x8*)(qb + ks * 32);
  }
  f32x4 o[8] = {};
  float mrow = -1e30f;  // running max for q=li (uniform across the 4 lg-groups)
  float lrow = 0.f;     // per-lane partial sum over this lane's 8 kv slots

  // hoisted per-lane staging pointers (advance by constant per iteration)
  const int kr0 = wave * 8 + (lane >> 4);
  const int kr1 = kr0 + 4;
  const u16* kp0 = Kb + (size_t)(n0base + kr0) * 2048 + h * 128 +
                   ((lane & 15) ^ (kr0 & 7)) * 8;
  const u16* kp1 = Kb + (size_t)(n0base + kr1) * 2048 + h * 128 +
                   ((lane & 15) ^ (kr1 & 7)) * 8;
  const int vGs = (lane & 7) ^ ((lane >> 3) & 7);
  const int vr0 = wave * 32 + ((lane >> 3) << 1) + (vGs >> 2);
  const u16* vp0 = VT + (size_t)(h * 128 + vr0) * 3200 + n0base + (vGs & 3) * 8;
  const int ldsoff = wave * 1024 + lane * 8;  // wave*2*512 + lane*8

  // V^T read offsets for the PV B-fragment (two 8B granules per f8):
  //   row r = f8*16+li, cols lg*4+{0..3} (slots j=0..3) and 16+lg*4+{0..3} (j=4..7).
  //   stored 16B-slot t of row-pair rp holds global granule t ^ (rp&7).
  const u32 vA = (u32)(((li & ~1) << 6) +
                       (((((li & 1) << 2) | (lg >> 1)) ^ ((li >> 1) & 7)) << 4) +
                       ((lg & 1) << 3));

#define STAGE(B)                                              \
  do {                                                        \
    gload_lds16(kp0, &Klds[B][0] + ldsoff);                   \
    gload_lds16(kp1, &Klds[B][0] + ldsoff + 512);             \
    gload_lds16(vp0, &Vlds[B][0] + ldsoff);                   \
    gload_lds16(vp0 + 16 * 3200, &Vlds[B][0] + ldsoff + 512); \
    kp0 += 65536;                                             \
    kp1 += 65536;                                             \
    vp0 += 32;                                                \
  } while (0)

  STAGE(0);
  asm volatile("s_waitcnt vmcnt(0)" ::: "memory");
  __syncthreads();

  for (int it = 0; it < 50; ++it) {
    const int buf = it & 1;
    if (it < 49) STAGE(buf ^ 1);  // async prefetch of next tile

    // QK^T with swapped operands: S^T[kv][q]
    f32x4 s0 = {0.f, 0.f, 0.f, 0.f}, s1 = {0.f, 0.f, 0.f, 0.f};
#pragma unroll
    for (int ks = 0; ks < 4; ks++) {
      const int g = (((ks * 4 + lg) ^ (li & 7)) * 8);
      bf16x8 k0 = *(const bf16x8*)&Klds[buf][li * 128 + g];
      bf16x8 k1 = *(const bf16x8*)&Klds[buf][(16 + li) * 128 + g];
      s0 = MFMA16(k0, qf[ks], s0);
      s1 = MFMA16(k1, qf[ks], s1);
    }
    // tile max for q=li: per-lane max over 8, then reduce over the 4 lg-groups
    float pm = fmaxf(fmaxf(fmaxf(s0[0], s0[1]), fmaxf(s0[2], s0[3])),
                     fmaxf(fmaxf(s1[0], s1[1]), fmaxf(s1[2], s1[3])));
    pm = fmaxf(pm, __shfl_xor(pm, 16));
    pm = fmaxf(pm, __shfl_xor(pm, 32));
    // defer-max (T13): common path skips the rescale entirely.
    if (__any(pm - mrow > 8.0f)) {
      const float mn = fmaxf(mrow, pm);
      const float alq = exp2f(mrow - mn);  // uniform across lg for this q
      mrow = mn;
      lrow *= alq;
      float alv[4];
#pragma unroll
      for (int i = 0; i < 4; i++) alv[i] = __shfl(alq, lg * 4 + i);
#pragma unroll
      for (int f8 = 0; f8 < 8; f8++) {
        o[f8][0] *= alv[0]; o[f8][1] *= alv[1];
        o[f8][2] *= alv[2]; o[f8][3] *= alv[3];
      }
    }
    f32x4 p0, p1;
#pragma unroll
    for (int i = 0; i < 4; i++) {
      p0[i] = exp2f(s0[i] - mrow);  // bounded by 2^8
      p1[i] = exp2f(s1[i] - mrow);
    }
    lrow += ((p0[0] + p0[1]) + (p0[2] + p0[3])) + ((p1[0] + p1[1]) + (p1[2] + p1[3]));
    u32 w0, w1, w2, w3;
    asm("v_cvt_pk_bf16_f32 %0, %1, %2" : "=v"(w0) : "v"(p0[0]), "v"(p0[1]));
    asm("v_cvt_pk_bf16_f32 %0, %1, %2" : "=v"(w1) : "v"(p0[2]), "v"(p0[3]));
    asm("v_cvt_pk_bf16_f32 %0, %1, %2" : "=v"(w2) : "v"(p1[0]), "v"(p1[1]));
    asm("v_cvt_pk_bf16_f32 %0, %1, %2" : "=v"(w3) : "v"(p1[2]), "v"(p1[3]));
    u32x4 paw = {w0, w1, w2, w3};
    bf16x8 pa = __builtin_bit_cast(bf16x8, paw);

    const char* vbp = (const char*)&Vlds[buf][0] + vA;
    const char* vbp2 = (const char*)&Vlds[buf][0] + (vA ^ 32);
#pragma unroll
    for (int f8 = 0; f8 < 8; f8++) {
      bf16x8 vf;
      *(u16x4*)&vf = *(const u16x4*)(vbp + f8 * 1024);
      *((u16x4*)&vf + 1) = *(const u16x4*)(vbp2 + f8 * 1024);
      o[f8] = MFMA16(pa, vf, o[f8]);
    }
    asm volatile("s_waitcnt vmcnt(0)" ::: "memory");  // next tile landed
    __syncthreads();
  }
#undef STAGE

  float lt = lrow;
  lt += __shfl_xor(lt, 16);
  lt += __shfl_xor(lt, 32);  // total denominator for q=li
  const float inv = 1.0f / lt;
  float invi[4];
#pragma unroll
  for (int i = 0; i < 4; i++) invi[i] = __shfl(inv, lg * 4 + i);
#pragma unroll
  for (int i = 0; i < 4; i++) {
    const int row = qrow0 + lg * 4 + i;
#pragma unroll
    for (int f8 = 0; f8 < 8; f8++)
      Opart[(size_t)split * 6553600 + (size_t)row * 2048 + h * 128 + f8 * 16 + li] =
          f2bf(o[f8][i] * invi[i]);
  }
  if (lane < 16) {
    const int row = qrow0 + li;
    const size_t mlb = ((size_t)(split * 16 + h) * 3200 + row) * 2;
    ml[mlb] = mrow;
    ml[mlb + 1] = lt;
  }
}

// ---------------- combine the two KV-split partials ----------------
__global__ __launch_bounds__(256) void attn_combine(const u16* __restrict__ op,
                                                    const float* __restrict__ ml,
                                                    u16* __restrict__ out) {
  const int row = blockIdx.x, tid = threadIdx.x;
  const int c8 = tid * 8, h = c8 >> 7;
  const size_t b0 = ((size_t)h * 3200 + row) * 2;
  const size_t b1 = ((size_t)(16 + h) * 3200 + row) * 2;
  const float m0 = ml[b0], l0 = ml[b0 + 1];
  const float m1 = ml[b1], l1 = ml[b1 + 1];
  const float M = fmaxf(m0, m1);
  const float w0 = exp2f(m0 - M) * l0, w1 = exp2f(m1 - M) * l1;
  const float inv = 1.0f / (w0 + w1);
  u16x8 a = *(const u16x8*)&op[(size_t)row * 2048 + c8];
  u16x8 b = *(const u16x8*)&op[6553600 + (size_t)row * 2048 + c8];
  u16x8 r;
#pragma unroll
  for (int j = 0; j < 8; j++)
    r[j] = f2bf((bf2f(a[j]) * w0 + bf2f(b[j]) * w1) * inv);
  *(u16x8*)&out[(size_t)row * 2048 + c8] = r;
}

// ---------------- launcher ----------------
extern "C" void kernel_launch(void* const* d_in, const int* in_sizes, int n_in,
                              void* d_out, int out_size, void* d_ws, size_t ws_size,
                              hipStream_t stream) {
  const float* x    = (const float*)d_in[0];
  const float* wq   = (const float*)d_in[1];
  const float* bq   = (const float*)d_in[2];
  const float* wk   = (const float*)d_in[3];
  const float* bk   = (const float*)d_in[4];
  const float* wv   = (const float*)d_in[5];
  const float* bv   = (const float*)d_in[6];
  const float* wo   = (const float*)d_in[7];
  const float* bo   = (const float*)d_in[8];
  const float* nqw  = (const float*)d_in[9];
  const float* nkw  = (const float*)d_in[10];
  const float* fcos = (const float*)d_in[11];
  const float* fsin = (const float*)d_in[12];

  const size_t NEED = 125304832;
  if (ws_size < NEED) return;
  char* ws = (char*)d_ws;
  u16* x_bf   = (u16*)(ws + 0);            // dead after V GEMM; ml reuses this region
  u16* wq_bf  = (u16*)(ws + 13107200);
  u16* wk_bf  = (u16*)(ws + 21495808);
  u16* wv_bf  = (u16*)(ws + 29884416);
  u16* wo_bf  = (u16*)(ws + 38273024);
  float* pre  = (float*)(ws + 46661632);   // 3200*2048 f32; reused as o-partials later
  u16* q_bf   = (u16*)(ws + 72876032);
  u16* k_bf   = (u16*)(ws + 85983232);
  u16* vT     = (u16*)(ws + 99090432);     // [2048][3200]
  u16* att_bf = (u16*)(ws + 112197632);
  u16* opart  = (u16*)(ws + 46661632);     // 2 x 3200*2048 bf16 (aliases pre)
  float* ml   = (float*)(ws + 0);          // 2*16*3200*2 f32 (aliases x_bf)

  cast_f32_bf16<<<3200, 256, 0, stream>>>(x, x_bf, 819200);
  cast_f32_bf16<<<2048, 256, 0, stream>>>(wq, wq_bf, 524288);
  cast_f32_bf16<<<2048, 256, 0, stream>>>(wk, wk_bf, 524288);
  cast_f32_bf16<<<2048, 256, 0, stream>>>(wv, wv_bf, 524288);
  cast_f32_bf16<<<2048, 256, 0, stream>>>(wo, wo_bf, 524288);

  const dim3 gg(25, 16);
  const float foldq = 1.4426950408889634f * 0.08838834764831843f;  // log2e / sqrt(128)

  gemm_nt<0><<<gg, 256, 0, stream>>>(x_bf, wq_bf, bq, (void*)pre);
  rms_rope<<<3200, 256, 0, stream>>>(pre, nqw, fcos, fsin, q_bf, foldq);
  gemm_nt<0><<<gg, 256, 0, stream>>>(x_bf, wk_bf, bk, (void*)pre);
  rms_rope<<<3200, 256, 0, stream>>>(pre, nkw, fcos, fsin, k_bf, 1.0f);
  gemm_nt<1><<<gg, 256, 0, stream>>>(x_bf, wv_bf, bv, (void*)pre);  // v bf16 into pre buf
  transpose_2d<<<dim3(50, 32), 256, 0, stream>>>((const u16*)pre, vT);
  attn_kernel<<<dim3(50, 16, 2), 256, 0, stream>>>(q_bf, k_bf, vT, opart, ml);
  attn_combine<<<3200, 256, 0, stream>>>(opart, ml, att_bf);
  gemm_nt<0><<<gg, 256, 0, stream>>>(att_bf, wo_bf, bo, d_out);  // f32 out -> d_out
}

// Round 6
// 447.085 us; speedup vs baseline: 1.0457x; 1.0457x over previous
//
#include <hip/hip_runtime.h>

typedef unsigned short u16;
typedef unsigned int u32;
typedef __attribute__((ext_vector_type(4))) float f32x4;
typedef __attribute__((ext_vector_type(8))) short bf16x8;   // 8 bf16 bit-patterns (4 VGPRs)
typedef __attribute__((ext_vector_type(8))) u16 u16x8;
typedef __attribute__((ext_vector_type(4))) u16 u16x4;

#define GLOB_AS __attribute__((address_space(1)))
#define LDS_AS  __attribute__((address_space(3)))

__device__ __forceinline__ void gload_lds16(const void* g, void* l) {
  // async global->LDS, 16B per lane, LDS dest = wave-uniform base + lane*16
  __builtin_amdgcn_global_load_lds((const GLOB_AS void*)g, (LDS_AS void*)l, 16, 0, 0);
}

__device__ __forceinline__ u16 f2bf(float f) {  // RNE float->bf16
  u32 u = __builtin_bit_cast(u32, f);
  u += 0x7fffu + ((u >> 16) & 1u);
  return (u16)(u >> 16);
}

__device__ __forceinline__ float bf2f(u16 b) {
  u32 u = (u32)b << 16;
  return __builtin_bit_cast(float, u);
}

#define MFMA16(a, b, c) __builtin_amdgcn_mfma_f32_16x16x32_bf16(a, b, c, 0, 0, 0)

// ---------------- elementwise cast f32 -> bf16 ----------------
__global__ __launch_bounds__(256) void cast_f32_bf16(const float* __restrict__ s,
                                                     u16* __restrict__ d, int n8) {
  int i = blockIdx.x * 256 + threadIdx.x;
  if (i >= n8) return;
  const f32x4* sp = (const f32x4*)s;
  f32x4 a = sp[2 * i], b = sp[2 * i + 1];
  u16x8 o;
  o[0] = f2bf(a[0]); o[1] = f2bf(a[1]); o[2] = f2bf(a[2]); o[3] = f2bf(a[3]);
  o[4] = f2bf(b[0]); o[5] = f2bf(b[1]); o[6] = f2bf(b[2]); o[7] = f2bf(b[3]);
  ((u16x8*)d)[i] = o;
}

// ---------------- fused QKV NT GEMM ----------------
// grid (25, 48): m0 = bx*128; by>>4 selects matrix {0:q,1:k,2:v}; n0 = (by&15)*128.
// One dispatch -> 1200 blocks (tail 94% vs 78% for 3x400).
__global__ __launch_bounds__(256) void gemm_qkv(const u16* __restrict__ A,
                                                const u16* __restrict__ Bq,
                                                const u16* __restrict__ Bk,
                                                const u16* __restrict__ Bv,
                                                const float* __restrict__ bq,
                                                const float* __restrict__ bk,
                                                const float* __restrict__ bv,
                                                float* __restrict__ Cq,
                                                float* __restrict__ Ck,
                                                u16* __restrict__ Cv) {
  constexpr int K = 2048, N = 2048;
  __shared__ u16 As[128 * 64];
  __shared__ u16 Bs[128 * 64];
  const int tid = threadIdx.x;
  const int wave = tid >> 6, lane = tid & 63;
  const int lg = lane >> 4, li = lane & 15;
  const int m0 = blockIdx.x * 128;
  const int mat = blockIdx.y >> 4;  // block-uniform
  const int n0 = (blockIdx.y & 15) * 128;
  const u16* B = (mat == 0) ? Bq : (mat == 1) ? Bk : Bv;
  const float* bias = (mat == 0) ? bq : (mat == 1) ? bk : bv;
  const int wr = (wave >> 1) * 64, wc = (wave & 1) * 64;

  const u16* Ag = A + (size_t)(m0 + 32 * wave + (lane >> 3)) * K + (lane & 7) * 8;
  const u16* Bg = B + (size_t)(n0 + 32 * wave + (lane >> 3)) * K + (lane & 7) * 8;
  u16* AsW = As + wave * 2048;
  u16* BsW = Bs + wave * 2048;

  f32x4 acc[4][4] = {};
  for (int k0 = 0; k0 < K; k0 += 64) {
    __syncthreads();
#pragma unroll
    for (int j = 0; j < 4; ++j) {
      gload_lds16(Ag + k0 + (size_t)(8 * j) * K, AsW + j * 512);
      gload_lds16(Bg + k0 + (size_t)(8 * j) * K, BsW + j * 512);
    }
    __syncthreads();
#pragma unroll
    for (int kk = 0; kk < 64; kk += 32) {
      bf16x8 af[4], bfr[4];
#pragma unroll
      for (int mi = 0; mi < 4; mi++)
        af[mi] = *(const bf16x8*)&As[(wr + mi * 16 + li) * 64 + kk + lg * 8];
#pragma unroll
      for (int ni = 0; ni < 4; ni++)
        bfr[ni] = *(const bf16x8*)&Bs[(wc + ni * 16 + li) * 64 + kk + lg * 8];
#pragma unroll
      for (int mi = 0; mi < 4; mi++)
#pragma unroll
        for (int ni = 0; ni < 4; ni++)
          acc[mi][ni] = MFMA16(af[mi], bfr[ni], acc[mi][ni]);
    }
  }
  float bcol[4];
#pragma unroll
  for (int ni = 0; ni < 4; ni++) bcol[ni] = bias[n0 + wc + ni * 16 + li];
  float* Cf = (mat == 0) ? Cq : Ck;
#pragma unroll
  for (int mi = 0; mi < 4; mi++) {
#pragma unroll
    for (int ni = 0; ni < 4; ni++) {
      const int gm = m0 + wr + mi * 16 + lg * 4;
      const int gn = n0 + wc + ni * 16 + li;
#pragma unroll
      for (int r = 0; r < 4; r++) {
        float v = acc[mi][ni][r] + bcol[ni];
        if (mat < 2)
          Cf[(size_t)(gm + r) * N + gn] = v;
        else
          Cv[(size_t)(gm + r) * N + gn] = f2bf(v);
      }
    }
  }
}

// ---------------- NT GEMM (out-proj): C[m][n] = sum_k A[m][k]*B[n][k] + bias[n] ----------------
template <int OUTM>  // 0: f32 out, 1: bf16 out
__global__ __launch_bounds__(256) void gemm_nt(const u16* __restrict__ A,
                                               const u16* __restrict__ B,
                                               const float* __restrict__ bias,
                                               void* __restrict__ C) {
  constexpr int K = 2048, N = 2048;
  __shared__ u16 As[128 * 64];
  __shared__ u16 Bs[128 * 64];
  const int tid = threadIdx.x;
  const int wave = tid >> 6, lane = tid & 63;
  const int lg = lane >> 4, li = lane & 15;
  const int m0 = blockIdx.x * 128, n0 = blockIdx.y * 128;
  const int wr = (wave >> 1) * 64, wc = (wave & 1) * 64;

  const u16* Ag = A + (size_t)(m0 + 32 * wave + (lane >> 3)) * K + (lane & 7) * 8;
  const u16* Bg = B + (size_t)(n0 + 32 * wave + (lane >> 3)) * K + (lane & 7) * 8;
  u16* AsW = As + wave * 2048;
  u16* BsW = Bs + wave * 2048;

  f32x4 acc[4][4] = {};
  for (int k0 = 0; k0 < K; k0 += 64) {
    __syncthreads();
#pragma unroll
    for (int j = 0; j < 4; ++j) {
      gload_lds16(Ag + k0 + (size_t)(8 * j) * K, AsW + j * 512);
      gload_lds16(Bg + k0 + (size_t)(8 * j) * K, BsW + j * 512);
    }
    __syncthreads();
#pragma unroll
    for (int kk = 0; kk < 64; kk += 32) {
      bf16x8 af[4], bfr[4];
#pragma unroll
      for (int mi = 0; mi < 4; mi++)
        af[mi] = *(const bf16x8*)&As[(wr + mi * 16 + li) * 64 + kk + lg * 8];
#pragma unroll
      for (int ni = 0; ni < 4; ni++)
        bfr[ni] = *(const bf16x8*)&Bs[(wc + ni * 16 + li) * 64 + kk + lg * 8];
#pragma unroll
      for (int mi = 0; mi < 4; mi++)
#pragma unroll
        for (int ni = 0; ni < 4; ni++)
          acc[mi][ni] = MFMA16(af[mi], bfr[ni], acc[mi][ni]);
    }
  }
  float bcol[4];
#pragma unroll
  for (int ni = 0; ni < 4; ni++) bcol[ni] = bias[n0 + wc + ni * 16 + li];
#pragma unroll
  for (int mi = 0; mi < 4; mi++) {
#pragma unroll
    for (int ni = 0; ni < 4; ni++) {
      const int gm = m0 + wr + mi * 16 + lg * 4;
      const int gn = n0 + wc + ni * 16 + li;
#pragma unroll
      for (int r = 0; r < 4; r++) {
        float v = acc[mi][ni][r] + bcol[ni];
        if constexpr (OUTM == 0)
          ((float*)C)[(size_t)(gm + r) * N + gn] = v;
        else
          ((u16*)C)[(size_t)(gm + r) * N + gn] = f2bf(v);
      }
    }
  }
}

// ---------------- fused RMSNorm (over 2048) + 3-axis RoPE, f32 -> bf16 ----------------
__global__ __launch_bounds__(256) void rms_rope(const float* __restrict__ pre,
                                                const float* __restrict__ w,
                                                const float* __restrict__ fcos,
                                                const float* __restrict__ fsin,
                                                u16* __restrict__ out, float fold) {
  const int l = blockIdx.x, tid = threadIdx.x;
  const float* row = pre + (size_t)l * 2048;
  const int d0 = tid * 8;
  f32x4 v0 = *(const f32x4*)(row + d0);
  f32x4 v1 = *(const f32x4*)(row + d0 + 4);
  float ss = v0[0] * v0[0] + v0[1] * v0[1] + v0[2] * v0[2] + v0[3] * v0[3] +
             v1[0] * v1[0] + v1[1] * v1[1] + v1[2] * v1[2] + v1[3] * v1[3];
#pragma unroll
  for (int m = 32; m; m >>= 1) ss += __shfl_xor(ss, m);
  __shared__ float red[4];
  if ((tid & 63) == 0) red[tid >> 6] = ss;
  __syncthreads();
  const float scale =
      rsqrtf((red[0] + red[1] + red[2] + red[3]) * (1.0f / 2048.0f) + 1e-6f) * fold;
  f32x4 w0 = *(const f32x4*)(w + d0);
  f32x4 w1 = *(const f32x4*)(w + d0 + 4);
  float xs[8];
#pragma unroll
  for (int j = 0; j < 4; j++) {
    xs[j] = v0[j] * w0[j] * scale;
    xs[4 + j] = v1[j] * w1[j] * scale;
  }
  const int f = l / 640, rem = l % 640;
  const int hh = rem >> 5, ww = rem & 31;
  const int cb = (d0 & 127) >> 1;
  u16x8 ov;
#pragma unroll
  for (int i = 0; i < 4; i++) {
    const int c = cb + i;
    const int prow = c < 22 ? f : (c < 43 ? hh : ww);  // S0=22, S0+S1=43
    const float fc = fcos[prow * 64 + c];
    const float fs = fsin[prow * 64 + c];
    const float xr = xs[2 * i], xi = xs[2 * i + 1];
    ov[2 * i] = f2bf(xr * fc - xi * fs);
    ov[2 * i + 1] = f2bf(xr * fs + xi * fc);
  }
  *(u16x8*)(out + (size_t)l * 2048 + d0) = ov;
}

// ---------------- bf16 transpose [3200][2048] -> [2048][3200] ----------------
__global__ __launch_bounds__(256) void transpose_2d(const u16* __restrict__ src,
                                                    u16* __restrict__ dst) {
  __shared__ u16 t[64][72];
  const int m0 = blockIdx.x * 64, n0 = blockIdx.y * 64;
  const int tid = threadIdx.x;
  const int r = tid >> 3, c8 = (tid & 7) * 8;
#pragma unroll
  for (int j = 0; j < 2; j++) {
    u16x8 v = *(const u16x8*)&src[(size_t)(m0 + r + 32 * j) * 2048 + n0 + c8];
#pragma unroll
    for (int e = 0; e < 8; e++) t[c8 + e][r + 32 * j] = v[e];
  }
  __syncthreads();
#pragma unroll
  for (int j = 0; j < 2; j++) {
    u16x8 v = *(const u16x8*)&t[r + 32 * j][c8];
    *(u16x8*)&dst[(size_t)(n0 + r + 32 * j) * 3200 + m0 + c8] = v;
  }
}

// ---------------- flash attention (round-4 version), KV-split x2, dbuf LDS K/V ----------------
__global__ __launch_bounds__(256) void attn_kernel(const u16* __restrict__ Q,
                                                   const u16* __restrict__ Kb,
                                                   const u16* __restrict__ VT,
                                                   u16* __restrict__ Opart,
                                                   float* __restrict__ ml) {
  __shared__ u16 Klds[2][32 * 128];
  __shared__ u16 Vlds[2][128 * 32];
  __shared__ u16 plds[4][16 * 36];
  const int tid = threadIdx.x, wave = tid >> 6, lane = tid & 63;
  const int lg = lane >> 4, li = lane & 15;

  // bijective XCD-aware remap: lid = x + 50y + 800z; xcd = lid&7 -> heads {2x,2x+1}
  const int lid = blockIdx.x + 50 * blockIdx.y + 800 * blockIdx.z;
  const int xcd = lid & 7, ixd = lid >> 3;
  const int h = xcd * 2 + (ixd & 1);
  const int rem = ixd >> 1;
  const int split = rem & 1;
  const int qrow0 = (rem >> 1) * 64 + wave * 16;
  const int n0base = split * 1600;

  u16* pw = plds[wave];

  bf16x8 qf[4];
  {
    const u16* qb = Q + (size_t)(qrow0 + li) * 2048 + h * 128 + lg * 8;
#pragma unroll
    for (int ks = 0; ks < 4; ks++) qf[ks] = *(const bf16x8*)(qb + ks * 32);
  }
  f32x4 o[8] = {};
  float mrow[4] = {-1e30f, -1e30f, -1e30f, -1e30f};
  float lrow[4] = {0.f, 0.f, 0.f, 0.f};

  // hoisted per-lane staging pointers (advance by constant per iteration)
  const int kr0 = wave * 8 + (lane >> 4);
  const int kr1 = kr0 + 4;
  const u16* kp0 = Kb + (size_t)(n0base + kr0) * 2048 + h * 128 +
                   ((lane & 15) ^ (kr0 & 7)) * 8;
  const u16* kp1 = Kb + (size_t)(n0base + kr1) * 2048 + h * 128 +
                   ((lane & 15) ^ (kr1 & 7)) * 8;
  const int vGs = (lane & 7) ^ ((lane >> 3) & 7);
  const int vr0 = wave * 32 + ((lane >> 3) << 1) + (vGs >> 2);
  const u16* vp0 = VT + (size_t)(h * 128 + vr0) * 3200 + n0base + (vGs & 3) * 8;
  const int ldsoff = wave * 1024 + lane * 8;  // wave*2*512 + lane*8

#define STAGE(B)                                              \
  do {                                                        \
    gload_lds16(kp0, &Klds[B][0] + ldsoff);                   \
    gload_lds16(kp1, &Klds[B][0] + ldsoff + 512);             \
    gload_lds16(vp0, &Vlds[B][0] + ldsoff);                   \
    gload_lds16(vp0 + 16 * 3200, &Vlds[B][0] + ldsoff + 512); \
    kp0 += 65536;                                             \
    kp1 += 65536;                                             \
    vp0 += 32;                                                \
  } while (0)

  STAGE(0);
  asm volatile("s_waitcnt vmcnt(0)" ::: "memory");
  __syncthreads();

  for (int it = 0; it < 50; ++it) {
    const int buf = it & 1;
    if (it < 49) STAGE(buf ^ 1);  // async prefetch of next tile

    f32x4 s0 = {0.f, 0.f, 0.f, 0.f}, s1 = {0.f, 0.f, 0.f, 0.f};
#pragma unroll
    for (int ks = 0; ks < 4; ks++) {
      const int g = (((ks * 4 + lg) ^ (li & 7)) * 8);
      bf16x8 k0 = *(const bf16x8*)&Klds[buf][li * 128 + g];
      bf16x8 k1 = *(const bf16x8*)&Klds[buf][(16 + li) * 128 + g];
      s0 = MFMA16(qf[ks], k0, s0);
      s1 = MFMA16(qf[ks], k1, s1);
    }
    // defer-max (T13): common path skips the shuffle-max chain AND the rescale.
    float need = -1e30f;
#pragma unroll
    for (int i = 0; i < 4; i++)
      need = fmaxf(need, fmaxf(s0[i], s1[i]) - mrow[i]);
    if (__any(need > 8.0f)) {
      float al[4];
#pragma unroll
      for (int i = 0; i < 4; i++) {
        float pm = fmaxf(s0[i], s1[i]);
        pm = fmaxf(pm, __shfl_xor(pm, 1));
        pm = fmaxf(pm, __shfl_xor(pm, 2));
        pm = fmaxf(pm, __shfl_xor(pm, 4));
        pm = fmaxf(pm, __shfl_xor(pm, 8));
        const float mn = fmaxf(mrow[i], pm);
        al[i] = exp2f(mrow[i] - mn);
        mrow[i] = mn;
      }
#pragma unroll
      for (int f8 = 0; f8 < 8; f8++) {
        o[f8][0] *= al[0]; o[f8][1] *= al[1]; o[f8][2] *= al[2]; o[f8][3] *= al[3];
      }
      lrow[0] *= al[0]; lrow[1] *= al[1]; lrow[2] *= al[2]; lrow[3] *= al[3];
    }
#pragma unroll
    for (int i = 0; i < 4; i++) {
      const float p0 = exp2f(s0[i] - mrow[i]);  // bounded by 2^8
      const float p1 = exp2f(s1[i] - mrow[i]);
      lrow[i] += p0 + p1;
      const int prow = (lg * 4 + i) * 36;
      pw[prow + li] = f2bf(p0);
      pw[prow + 16 + li] = f2bf(p1);
    }
    // wave-synchronous LDS transpose: b16 writes above, b64 reads below (cross-lane)
    asm volatile("s_waitcnt lgkmcnt(0)" ::: "memory");
    bf16x8 pa;
    {
      const u16* pr = &pw[li * 36 + lg * 8];
      u16x4 a0 = *(const u16x4*)pr;
      u16x4 a1 = *(const u16x4*)(pr + 4);
      pa[0] = a0[0]; pa[1] = a0[1]; pa[2] = a0[2]; pa[3] = a0[3];
      pa[4] = a1[0]; pa[5] = a1[1]; pa[6] = a1[2]; pa[7] = a1[3];
    }
    const int Gl = ((li & 1) * 4 + lg) ^ ((li >> 1) & 7);  // swizzled V read granule
#pragma unroll
    for (int f8 = 0; f8 < 8; f8++) {
      bf16x8 vf = *(const bf16x8*)&Vlds[buf][(f8 * 16 + (li & ~1) + (Gl >> 2)) * 32 +
                                            (Gl & 3) * 8];
      o[f8] = MFMA16(pa, vf, o[f8]);
    }
    asm volatile("s_waitcnt vmcnt(0)" ::: "memory");  // next tile landed
    __syncthreads();
  }
#undef STAGE

#pragma unroll
  for (int i = 0; i < 4; i++) {
    float lt = lrow[i];
    lt += __shfl_xor(lt, 1);
    lt += __shfl_xor(lt, 2);
    lt += __shfl_xor(lt, 4);
    lt += __shfl_xor(lt, 8);
    const float inv = 1.0f / lt;
    const int row = qrow0 + lg * 4 + i;
#pragma unroll
    for (int f8 = 0; f8 < 8; f8++)
      Opart[(size_t)split * 6553600 + (size_t)row * 2048 + h * 128 + f8 * 16 + li] =
          f2bf(o[f8][i] * inv);
    if (li == 0) {
      const size_t mlb = ((size_t)(split * 16 + h) * 3200 + row) * 2;
      ml[mlb] = mrow[i];
      ml[mlb + 1] = lt;
    }
  }
}

// ---------------- combine the two KV-split partials ----------------
__global__ __launch_bounds__(256) void attn_combine(const u16* __restrict__ op,
                                                    const float* __restrict__ ml,
                                                    u16* __restrict__ out) {
  const int row = blockIdx.x, tid = threadIdx.x;
  const int c8 = tid * 8, h = c8 >> 7;
  const size_t b0 = ((size_t)h * 3200 + row) * 2;
  const size_t b1 = ((size_t)(16 + h) * 3200 + row) * 2;
  const float m0 = ml[b0], l0 = ml[b0 + 1];
  const float m1 = ml[b1], l1 = ml[b1 + 1];
  const float M = fmaxf(m0, m1);
  const float w0 = exp2f(m0 - M) * l0, w1 = exp2f(m1 - M) * l1;
  const float inv = 1.0f / (w0 + w1);
  u16x8 a = *(const u16x8*)&op[(size_t)row * 2048 + c8];
  u16x8 b = *(const u16x8*)&op[6553600 + (size_t)row * 2048 + c8];
  u16x8 r;
#pragma unroll
  for (int j = 0; j < 8; j++)
    r[j] = f2bf((bf2f(a[j]) * w0 + bf2f(b[j]) * w1) * inv);
  *(u16x8*)&out[(size_t)row * 2048 + c8] = r;
}

// ---------------- launcher ----------------
extern "C" void kernel_launch(void* const* d_in, const int* in_sizes, int n_in,
                              void* d_out, int out_size, void* d_ws, size_t ws_size,
                              hipStream_t stream) {
  const float* x    = (const float*)d_in[0];
  const float* wq   = (const float*)d_in[1];
  const float* bq   = (const float*)d_in[2];
  const float* wk   = (const float*)d_in[3];
  const float* bk   = (const float*)d_in[4];
  const float* wv   = (const float*)d_in[5];
  const float* bv   = (const float*)d_in[6];
  const float* wo   = (const float*)d_in[7];
  const float* bo   = (const float*)d_in[8];
  const float* nqw  = (const float*)d_in[9];
  const float* nkw  = (const float*)d_in[10];
  const float* fcos = (const float*)d_in[11];
  const float* fsin = (const float*)d_in[12];

  const size_t NEED = 125304832;
  if (ws_size < NEED) return;
  char* ws = (char*)d_ws;
  // Lifetime-based layout (peak exactly NEED):
  u16* x_bf   = (u16*)(ws + 0);            // dead after gemm_qkv; ml reuses
  u16* wq_bf  = (u16*)(ws + 13107200);
  u16* wk_bf  = (u16*)(ws + 21495808);
  u16* wv_bf  = (u16*)(ws + 29884416);
  u16* wo_bf  = (u16*)(ws + 38273024);
  float* preq = (float*)(ws + 46661632);   // 26.2MB, dead after rms_rope(q)
  float* prek = (float*)(ws + 72876032);   // 26.2MB, dead after rms_rope(k)
  u16* v_bf   = (u16*)(ws + 99090432);     // dead after transpose
  u16* q_bf   = (u16*)(ws + 112197632);
  u16* k_bf   = (u16*)(ws + 46661632);     // aliases preq (dead)
  u16* vT     = (u16*)(ws + 59768832);     // aliases preq tail [2048][3200]
  u16* opart  = (u16*)(ws + 72876032);     // aliases prek (dead), 2x13.1MB
  float* ml   = (float*)(ws + 0);          // aliases x_bf (dead), 0.8MB
  u16* att_bf = (u16*)(ws + 99090432);     // aliases v_bf (dead)

  cast_f32_bf16<<<3200, 256, 0, stream>>>(x, x_bf, 819200);
  cast_f32_bf16<<<2048, 256, 0, stream>>>(wq, wq_bf, 524288);
  cast_f32_bf16<<<2048, 256, 0, stream>>>(wk, wk_bf, 524288);
  cast_f32_bf16<<<2048, 256, 0, stream>>>(wv, wv_bf, 524288);
  cast_f32_bf16<<<2048, 256, 0, stream>>>(wo, wo_bf, 524288);

  const float foldq = 1.4426950408889634f * 0.08838834764831843f;  // log2e / sqrt(128)

  gemm_qkv<<<dim3(25, 48), 256, 0, stream>>>(x_bf, wq_bf, wk_bf, wv_bf, bq, bk, bv,
                                             preq, prek, v_bf);
  rms_rope<<<3200, 256, 0, stream>>>(preq, nqw, fcos, fsin, q_bf, foldq);
  rms_rope<<<3200, 256, 0, stream>>>(prek, nkw, fcos, fsin, k_bf, 1.0f);
  transpose_2d<<<dim3(50, 32), 256, 0, stream>>>(v_bf, vT);
  attn_kernel<<<dim3(50, 16, 2), 256, 0, stream>>>(q_bf, k_bf, vT, opart, ml);
  attn_combine<<<3200, 256, 0, stream>>>(opart, ml, att_bf);
  gemm_nt<0><<<dim3(25, 16), 256, 0, stream>>>(att_bf, wo_bf, bo, d_out);
}

// Round 7
// 407.803 us; speedup vs baseline: 1.1465x; 1.0963x over previous
//
#include <hip/hip_runtime.h>

typedef unsigned short u16;
typedef unsigned int u32;
typedef __attribute__((ext_vector_type(4))) float f32x4;
typedef __attribute__((ext_vector_type(8))) short bf16x8;   // 8 bf16 bit-patterns (4 VGPRs)
typedef __attribute__((ext_vector_type(8))) u16 u16x8;
typedef __attribute__((ext_vector_type(4))) u16 u16x4;
typedef __attribute__((ext_vector_type(4))) u32 u32x4;

#define GLOB_AS __attribute__((address_space(1)))
#define LDS_AS  __attribute__((address_space(3)))

__device__ __forceinline__ void gload_lds16(const void* g, void* l) {
  // async global->LDS, 16B per lane, LDS dest = wave-uniform base + lane*16
  __builtin_amdgcn_global_load_lds((const GLOB_AS void*)g, (LDS_AS void*)l, 16, 0, 0);
}

__device__ __forceinline__ u16 f2bf(float f) {  // RNE float->bf16
  u32 u = __builtin_bit_cast(u32, f);
  u += 0x7fffu + ((u >> 16) & 1u);
  return (u16)(u >> 16);
}

__device__ __forceinline__ float bf2f(u16 b) {
  u32 u = (u32)b << 16;
  return __builtin_bit_cast(float, u);
}

#define MFMA16(a, b, c) __builtin_amdgcn_mfma_f32_16x16x32_bf16(a, b, c, 0, 0, 0)

// ---------------- fused cast f32 -> bf16 for x + 4 weight matrices ----------------
__global__ __launch_bounds__(256) void cast_all(const float* __restrict__ x,
                                                const float* __restrict__ wq,
                                                const float* __restrict__ wk,
                                                const float* __restrict__ wv,
                                                const float* __restrict__ wo,
                                                u16* __restrict__ xb, u16* __restrict__ wqb,
                                                u16* __restrict__ wkb, u16* __restrict__ wvb,
                                                u16* __restrict__ wob) {
  int i = blockIdx.x * 256 + threadIdx.x;  // 8-element units; boundaries block-uniform
  const float* s;
  u16* d;
  int off;
  if (i < 819200)       { s = x;  d = xb;  off = i; }
  else if (i < 1343488) { s = wq; d = wqb; off = i - 819200; }
  else if (i < 1867776) { s = wk; d = wkb; off = i - 1343488; }
  else if (i < 2392064) { s = wv; d = wvb; off = i - 1867776; }
  else                  { s = wo; d = wob; off = i - 2392064; }
  f32x4 a = ((const f32x4*)s)[2 * off], b = ((const f32x4*)s)[2 * off + 1];
  u16x8 o;
  o[0] = f2bf(a[0]); o[1] = f2bf(a[1]); o[2] = f2bf(a[2]); o[3] = f2bf(a[3]);
  o[4] = f2bf(b[0]); o[5] = f2bf(b[1]); o[6] = f2bf(b[2]); o[7] = f2bf(b[3]);
  ((u16x8*)d)[off] = o;
}

// ---------------- fused QKV NT GEMM ----------------
__global__ __launch_bounds__(256) void gemm_qkv(const u16* __restrict__ A,
                                                const u16* __restrict__ Bq,
                                                const u16* __restrict__ Bk,
                                                const u16* __restrict__ Bv,
                                                const float* __restrict__ bq,
                                                const float* __restrict__ bk,
                                                const float* __restrict__ bv,
                                                float* __restrict__ Cq,
                                                float* __restrict__ Ck,
                                                u16* __restrict__ Cv) {
  constexpr int K = 2048, N = 2048;
  __shared__ u16 As[128 * 64];
  __shared__ u16 Bs[128 * 64];
  const int tid = threadIdx.x;
  const int wave = tid >> 6, lane = tid & 63;
  const int lg = lane >> 4, li = lane & 15;
  const int m0 = blockIdx.x * 128;
  const int mat = blockIdx.y >> 4;  // block-uniform
  const int n0 = (blockIdx.y & 15) * 128;
  const u16* B = (mat == 0) ? Bq : (mat == 1) ? Bk : Bv;
  const float* bias = (mat == 0) ? bq : (mat == 1) ? bk : bv;
  const int wr = (wave >> 1) * 64, wc = (wave & 1) * 64;

  const u16* Ag = A + (size_t)(m0 + 32 * wave + (lane >> 3)) * K + (lane & 7) * 8;
  const u16* Bg = B + (size_t)(n0 + 32 * wave + (lane >> 3)) * K + (lane & 7) * 8;
  u16* AsW = As + wave * 2048;
  u16* BsW = Bs + wave * 2048;

  f32x4 acc[4][4] = {};
  for (int k0 = 0; k0 < K; k0 += 64) {
    __syncthreads();
#pragma unroll
    for (int j = 0; j < 4; ++j) {
      gload_lds16(Ag + k0 + (size_t)(8 * j) * K, AsW + j * 512);
      gload_lds16(Bg + k0 + (size_t)(8 * j) * K, BsW + j * 512);
    }
    __syncthreads();
#pragma unroll
    for (int kk = 0; kk < 64; kk += 32) {
      bf16x8 af[4], bfr[4];
#pragma unroll
      for (int mi = 0; mi < 4; mi++)
        af[mi] = *(const bf16x8*)&As[(wr + mi * 16 + li) * 64 + kk + lg * 8];
#pragma unroll
      for (int ni = 0; ni < 4; ni++)
        bfr[ni] = *(const bf16x8*)&Bs[(wc + ni * 16 + li) * 64 + kk + lg * 8];
#pragma unroll
      for (int mi = 0; mi < 4; mi++)
#pragma unroll
        for (int ni = 0; ni < 4; ni++)
          acc[mi][ni] = MFMA16(af[mi], bfr[ni], acc[mi][ni]);
    }
  }
  float bcol[4];
#pragma unroll
  for (int ni = 0; ni < 4; ni++) bcol[ni] = bias[n0 + wc + ni * 16 + li];
  float* Cf = (mat == 0) ? Cq : Ck;
#pragma unroll
  for (int mi = 0; mi < 4; mi++) {
#pragma unroll
    for (int ni = 0; ni < 4; ni++) {
      const int gm = m0 + wr + mi * 16 + lg * 4;
      const int gn = n0 + wc + ni * 16 + li;
#pragma unroll
      for (int r = 0; r < 4; r++) {
        float v = acc[mi][ni][r] + bcol[ni];
        if (mat < 2)
          Cf[(size_t)(gm + r) * N + gn] = v;
        else
          Cv[(size_t)(gm + r) * N + gn] = f2bf(v);
      }
    }
  }
}

// ---------------- NT GEMM (out-proj) ----------------
template <int OUTM>
__global__ __launch_bounds__(256) void gemm_nt(const u16* __restrict__ A,
                                               const u16* __restrict__ B,
                                               const float* __restrict__ bias,
                                               void* __restrict__ C) {
  constexpr int K = 2048, N = 2048;
  __shared__ u16 As[128 * 64];
  __shared__ u16 Bs[128 * 64];
  const int tid = threadIdx.x;
  const int wave = tid >> 6, lane = tid & 63;
  const int lg = lane >> 4, li = lane & 15;
  const int m0 = blockIdx.x * 128, n0 = blockIdx.y * 128;
  const int wr = (wave >> 1) * 64, wc = (wave & 1) * 64;

  const u16* Ag = A + (size_t)(m0 + 32 * wave + (lane >> 3)) * K + (lane & 7) * 8;
  const u16* Bg = B + (size_t)(n0 + 32 * wave + (lane >> 3)) * K + (lane & 7) * 8;
  u16* AsW = As + wave * 2048;
  u16* BsW = Bs + wave * 2048;

  f32x4 acc[4][4] = {};
  for (int k0 = 0; k0 < K; k0 += 64) {
    __syncthreads();
#pragma unroll
    for (int j = 0; j < 4; ++j) {
      gload_lds16(Ag + k0 + (size_t)(8 * j) * K, AsW + j * 512);
      gload_lds16(Bg + k0 + (size_t)(8 * j) * K, BsW + j * 512);
    }
    __syncthreads();
#pragma unroll
    for (int kk = 0; kk < 64; kk += 32) {
      bf16x8 af[4], bfr[4];
#pragma unroll
      for (int mi = 0; mi < 4; mi++)
        af[mi] = *(const bf16x8*)&As[(wr + mi * 16 + li) * 64 + kk + lg * 8];
#pragma unroll
      for (int ni = 0; ni < 4; ni++)
        bfr[ni] = *(const bf16x8*)&Bs[(wc + ni * 16 + li) * 64 + kk + lg * 8];
#pragma unroll
      for (int mi = 0; mi < 4; mi++)
#pragma unroll
        for (int ni = 0; ni < 4; ni++)
          acc[mi][ni] = MFMA16(af[mi], bfr[ni], acc[mi][ni]);
    }
  }
  float bcol[4];
#pragma unroll
  for (int ni = 0; ni < 4; ni++) bcol[ni] = bias[n0 + wc + ni * 16 + li];
#pragma unroll
  for (int mi = 0; mi < 4; mi++) {
#pragma unroll
    for (int ni = 0; ni < 4; ni++) {
      const int gm = m0 + wr + mi * 16 + lg * 4;
      const int gn = n0 + wc + ni * 16 + li;
#pragma unroll
      for (int r = 0; r < 4; r++) {
        float v = acc[mi][ni][r] + bcol[ni];
        if constexpr (OUTM == 0)
          ((float*)C)[(size_t)(gm + r) * N + gn] = v;
        else
          ((u16*)C)[(size_t)(gm + r) * N + gn] = f2bf(v);
      }
    }
  }
}

// ---------------- fused RMSNorm + 3-axis RoPE ----------------
__global__ __launch_bounds__(256) void rms_rope(const float* __restrict__ pre,
                                                const float* __restrict__ w,
                                                const float* __restrict__ fcos,
                                                const float* __restrict__ fsin,
                                                u16* __restrict__ out, float fold) {
  const int l = blockIdx.x, tid = threadIdx.x;
  const float* row = pre + (size_t)l * 2048;
  const int d0 = tid * 8;
  f32x4 v0 = *(const f32x4*)(row + d0);
  f32x4 v1 = *(const f32x4*)(row + d0 + 4);
  float ss = v0[0] * v0[0] + v0[1] * v0[1] + v0[2] * v0[2] + v0[3] * v0[3] +
             v1[0] * v1[0] + v1[1] * v1[1] + v1[2] * v1[2] + v1[3] * v1[3];
#pragma unroll
  for (int m = 32; m; m >>= 1) ss += __shfl_xor(ss, m);
  __shared__ float red[4];
  if ((tid & 63) == 0) red[tid >> 6] = ss;
  __syncthreads();
  const float scale =
      rsqrtf((red[0] + red[1] + red[2] + red[3]) * (1.0f / 2048.0f) + 1e-6f) * fold;
  f32x4 w0 = *(const f32x4*)(w + d0);
  f32x4 w1 = *(const f32x4*)(w + d0 + 4);
  float xs[8];
#pragma unroll
  for (int j = 0; j < 4; j++) {
    xs[j] = v0[j] * w0[j] * scale;
    xs[4 + j] = v1[j] * w1[j] * scale;
  }
  const int f = l / 640, rem = l % 640;
  const int hh = rem >> 5, ww = rem & 31;
  const int cb = (d0 & 127) >> 1;
  u16x8 ov;
#pragma unroll
  for (int i = 0; i < 4; i++) {
    const int c = cb + i;
    const int prow = c < 22 ? f : (c < 43 ? hh : ww);  // S0=22, S0+S1=43
    const float fc = fcos[prow * 64 + c];
    const float fs = fsin[prow * 64 + c];
    const float xr = xs[2 * i], xi = xs[2 * i + 1];
    ov[2 * i] = f2bf(xr * fc - xi * fs);
    ov[2 * i + 1] = f2bf(xr * fs + xi * fc);
  }
  *(u16x8*)(out + (size_t)l * 2048 + d0) = ov;
}

// ---------------- bf16 transpose [3200][2048] -> [2048][3200], pi-permuted ----------------
// Output column order within each 32-block of the kv dim: col 8c+e holds
// src kv (e<4 ? 4c+e : 16+4c+(e-4)), matching the PV contraction ordering.
__global__ __launch_bounds__(256) void transpose_2d(const u16* __restrict__ src,
                                                    u16* __restrict__ dst) {
  __shared__ u16 t[64][72];
  const int m0 = blockIdx.x * 64, n0 = blockIdx.y * 64;
  const int tid = threadIdx.x;
  const int r = tid >> 3, c8 = (tid & 7) * 8;
#pragma unroll
  for (int j = 0; j < 2; j++) {
    u16x8 v = *(const u16x8*)&src[(size_t)(m0 + r + 32 * j) * 2048 + n0 + c8];
#pragma unroll
    for (int e = 0; e < 8; e++) t[c8 + e][r + 32 * j] = v[e];
  }
  __syncthreads();
  const int b = (c8 >> 5) * 32;       // 32-block base within tile
  const int cc = ((c8 >> 3) & 3) * 4; // 4-col group
#pragma unroll
  for (int j = 0; j < 2; j++) {
    const u16* trow = &t[r + 32 * j][0];
    u16x4 lo = *(const u16x4*)&trow[b + cc];
    u16x4 hi = *(const u16x4*)&trow[b + 16 + cc];
    u16x8 v;
    v[0] = lo[0]; v[1] = lo[1]; v[2] = lo[2]; v[3] = lo[3];
    v[4] = hi[0]; v[5] = hi[1]; v[6] = hi[2]; v[7] = hi[3];
    *(u16x8*)&dst[(size_t)(n0 + r + 32 * j) * 3200 + m0 + c8] = v;
  }
}

// ---------------- flash attention v3: swapped QK^T, KVBLK=64, counted-vmcnt pipeline ----------------
// grid (50,16,2) XCD-remapped. 4 waves x 16 q-rows. Swapped mfma(K,Q) -> lane owns q=li,
// kv = {16t+4lg+i}. In-register softmax (scalar m,l per lane); P packed via cvt_pk;
// PV B-frag = single b128 read of pi-permuted V^T tile (K-style XOR banking).
__global__ __launch_bounds__(256) void attn_kernel(const u16* __restrict__ Q,
                                                   const u16* __restrict__ Kb,
                                                   const u16* __restrict__ VT,
                                                   u16* __restrict__ Opart,
                                                   float* __restrict__ ml) {
  __shared__ u16 Klds[2][64 * 128];
  __shared__ u16 Vlds[2][128 * 64];
  const int tid = threadIdx.x, wave = tid >> 6, lane = tid & 63;
  const int lg = lane >> 4, li = lane & 15;

  const int lid = blockIdx.x + 50 * blockIdx.y + 800 * blockIdx.z;
  const int xcd = lid & 7, ixd = lid >> 3;
  const int h = xcd * 2 + (ixd & 1);
  const int rem = ixd >> 1;
  const int split = rem & 1;
  const int qrow0 = (rem >> 1) * 64 + wave * 16;
  const int n0base = split * 1600;

  bf16x8 qf[4];
  {
    const u16* qb = Q + (size_t)(qrow0 + li) * 2048 + h * 128 + lg * 8;
#pragma unroll
    for (int ks = 0; ks < 4; ks++) qf[ks] = *(const bf16x8*)(qb + ks * 32);
  }
  f32x4 o[8] = {};
  float mrow = -1e30f;  // running max for q=li (uniform across lg-groups)
  float lrow = 0.f;     // per-lane partial over this lane's 16 kv slots

  // K staging: wave stages rows 16w..16w+15; load j covers rows 16w+4j+(lane>>4),
  // LDS slot lane&15 holds global granule slot^(row&7).
  const int klp = lane >> 4;
  const int kg0 = (lane & 15) ^ klp;            // row&7 = (4j+klp)&7 -> klp for even j
  const int kdg8 = ((kg0 ^ 4) - kg0) * 8;       // odd-j granule delta (u16 units)
  const u16* kp = Kb + (size_t)(n0base + wave * 16 + klp) * 2048 + h * 128 + kg0 * 8;
  // V staging: wave stages d-rows 32w..32w+31; load j rows 32w+8j+(lane>>3),
  // slot lane&7 holds granule slot^(row&7), row&7 = lane>>3.
  const int vlp = lane >> 3;
  const int vg = (lane & 7) ^ vlp;
  const u16* vp = VT + (size_t)(h * 128 + wave * 32 + vlp) * 3200 + n0base + vg * 8;
  const u32 dstoff = wave * 2048 + lane * 8;  // u16 units; +512 per load j
  int sb = 0;

#define STAGE()                                       \
  do {                                                \
    u16* kd = &Klds[sb][0] + dstoff;                  \
    u16* vd = &Vlds[sb][0] + dstoff;                  \
    gload_lds16(kp, kd);                              \
    gload_lds16(kp + 4 * 2048 + kdg8, kd + 512);      \
    gload_lds16(kp + 8 * 2048, kd + 1024);            \
    gload_lds16(kp + 12 * 2048 + kdg8, kd + 1536);    \
    gload_lds16(vp, vd);                              \
    gload_lds16(vp + 8 * 3200, vd + 512);             \
    gload_lds16(vp + 16 * 3200, vd + 1024);           \
    gload_lds16(vp + 24 * 3200, vd + 1536);           \
    kp += 64 * 2048;                                  \
    vp += 64;                                         \
    sb ^= 1;                                          \
  } while (0)

  STAGE();  // iter 0
  STAGE();  // iter 1

  for (int it = 0; it < 25; ++it) {
    const int buf = it & 1;
    if (it < 24)
      asm volatile("s_waitcnt vmcnt(8)" ::: "memory");  // this iter's 8 landed
    else
      asm volatile("s_waitcnt vmcnt(0)" ::: "memory");
    __builtin_amdgcn_s_barrier();

    // QK^T swapped: s4[t][i] = S[kv=16t+4lg+i][q=li]
    f32x4 s4[4] = {};
#pragma unroll
    for (int t = 0; t < 4; t++)
#pragma unroll
      for (int ks = 0; ks < 4; ks++) {
        const bf16x8 kf = *(const bf16x8*)&Klds[buf][(t * 16 + li) * 128 +
                                                     ((ks * 4 + lg) ^ (li & 7)) * 8];
        s4[t] = MFMA16(kf, qf[ks], s4[t]);
      }
    // tile max for q=li
    float pm = fmaxf(fmaxf(fmaxf(s4[0][0], s4[0][1]), fmaxf(s4[0][2], s4[0][3])),
                     fmaxf(fmaxf(s4[1][0], s4[1][1]), fmaxf(s4[1][2], s4[1][3])));
    pm = fmaxf(pm, fmaxf(fmaxf(fmaxf(s4[2][0], s4[2][1]), fmaxf(s4[2][2], s4[2][3])),
                         fmaxf(fmaxf(s4[3][0], s4[3][1]), fmaxf(s4[3][2], s4[3][3]))));
    pm = fmaxf(pm, __shfl_xor(pm, 16));
    pm = fmaxf(pm, __shfl_xor(pm, 32));
    if (__any(pm - mrow > 8.0f)) {  // defer-max (T13)
      const float mn = fmaxf(mrow, pm);
      const float alq = exp2f(mrow - mn);
      mrow = mn;
      lrow *= alq;
      float alv[4];
#pragma unroll
      for (int i = 0; i < 4; i++) alv[i] = __shfl(alq, lg * 4 + i);
#pragma unroll
      for (int f8 = 0; f8 < 8; f8++) {
        o[f8][0] *= alv[0]; o[f8][1] *= alv[1];
        o[f8][2] *= alv[2]; o[f8][3] *= alv[3];
      }
    }
    f32x4 p[4];
#pragma unroll
    for (int t = 0; t < 4; t++)
#pragma unroll
      for (int i = 0; i < 4; i++) p[t][i] = exp2f(s4[t][i] - mrow);  // <= 2^8
    lrow += ((p[0][0] + p[0][1]) + (p[0][2] + p[0][3])) +
            ((p[1][0] + p[1][1]) + (p[1][2] + p[1][3])) +
            ((p[2][0] + p[2][1]) + (p[2][2] + p[2][3])) +
            ((p[3][0] + p[3][1]) + (p[3][2] + p[3][3]));
    u32 wp[8];
    asm("v_cvt_pk_bf16_f32 %0, %1, %2" : "=v"(wp[0]) : "v"(p[0][0]), "v"(p[0][1]));
    asm("v_cvt_pk_bf16_f32 %0, %1, %2" : "=v"(wp[1]) : "v"(p[0][2]), "v"(p[0][3]));
    asm("v_cvt_pk_bf16_f32 %0, %1, %2" : "=v"(wp[2]) : "v"(p[1][0]), "v"(p[1][1]));
    asm("v_cvt_pk_bf16_f32 %0, %1, %2" : "=v"(wp[3]) : "v"(p[1][2]), "v"(p[1][3]));
    asm("v_cvt_pk_bf16_f32 %0, %1, %2" : "=v"(wp[4]) : "v"(p[2][0]), "v"(p[2][1]));
    asm("v_cvt_pk_bf16_f32 %0, %1, %2" : "=v"(wp[5]) : "v"(p[2][2]), "v"(p[2][3]));
    asm("v_cvt_pk_bf16_f32 %0, %1, %2" : "=v"(wp[6]) : "v"(p[3][0]), "v"(p[3][1]));
    asm("v_cvt_pk_bf16_f32 %0, %1, %2" : "=v"(wp[7]) : "v"(p[3][2]), "v"(p[3][3]));
    u32x4 paw0 = {wp[0], wp[1], wp[2], wp[3]};
    u32x4 paw1 = {wp[4], wp[5], wp[6], wp[7]};
    const bf16x8 pa0 = __builtin_bit_cast(bf16x8, paw0);
    const bf16x8 pa1 = __builtin_bit_cast(bf16x8, paw1);

    // PV: vf = single b128 of pi-permuted V^T tile (cols 32tt+8lg..+7)
#pragma unroll
    for (int tt = 0; tt < 2; tt++)
#pragma unroll
      for (int f8 = 0; f8 < 8; f8++) {
        const bf16x8 vf = *(const bf16x8*)&Vlds[buf][(f8 * 16 + li) * 64 +
                                                     ((tt * 4 + lg) ^ (li & 7)) * 8];
        o[f8] = MFMA16(tt ? pa1 : pa0, vf, o[f8]);
      }
    __builtin_amdgcn_s_barrier();  // all waves done reading buf
    if (it <= 22) STAGE();         // refill buf for iter it+2
  }
#undef STAGE

  float lt = lrow;
  lt += __shfl_xor(lt, 16);
  lt += __shfl_xor(lt, 32);
  const float inv = 1.0f / lt;
  float invi[4];
#pragma unroll
  for (int i = 0; i < 4; i++) invi[i] = __shfl(inv, lg * 4 + i);
#pragma unroll
  for (int i = 0; i < 4; i++) {
    const int row = qrow0 + lg * 4 + i;
#pragma unroll
    for (int f8 = 0; f8 < 8; f8++)
      Opart[(size_t)split * 6553600 + (size_t)row * 2048 + h * 128 + f8 * 16 + li] =
          f2bf(o[f8][i] * invi[i]);
  }
  if (lane < 16) {
    const int row = qrow0 + li;
    const size_t mlb = ((size_t)(split * 16 + h) * 3200 + row) * 2;
    ml[mlb] = mrow;
    ml[mlb + 1] = lt;
  }
}

// ---------------- combine the two KV-split partials ----------------
__global__ __launch_bounds__(256) void attn_combine(const u16* __restrict__ op,
                                                    const float* __restrict__ ml,
                                                    u16* __restrict__ out) {
  const int row = blockIdx.x, tid = threadIdx.x;
  const int c8 = tid * 8, h = c8 >> 7;
  const size_t b0 = ((size_t)h * 3200 + row) * 2;
  const size_t b1 = ((size_t)(16 + h) * 3200 + row) * 2;
  const float m0 = ml[b0], l0 = ml[b0 + 1];
  const float m1 = ml[b1], l1 = ml[b1 + 1];
  const float M = fmaxf(m0, m1);
  const float w0 = exp2f(m0 - M) * l0, w1 = exp2f(m1 - M) * l1;
  const float inv = 1.0f / (w0 + w1);
  u16x8 a = *(const u16x8*)&op[(size_t)row * 2048 + c8];
  u16x8 b = *(const u16x8*)&op[6553600 + (size_t)row * 2048 + c8];
  u16x8 r;
#pragma unroll
  for (int j = 0; j < 8; j++)
    r[j] = f2bf((bf2f(a[j]) * w0 + bf2f(b[j]) * w1) * inv);
  *(u16x8*)&out[(size_t)row * 2048 + c8] = r;
}

// ---------------- launcher ----------------
extern "C" void kernel_launch(void* const* d_in, const int* in_sizes, int n_in,
                              void* d_out, int out_size, void* d_ws, size_t ws_size,
                              hipStream_t stream) {
  const float* x    = (const float*)d_in[0];
  const float* wq   = (const float*)d_in[1];
  const float* bq   = (const float*)d_in[2];
  const float* wk   = (const float*)d_in[3];
  const float* bk   = (const float*)d_in[4];
  const float* wv   = (const float*)d_in[5];
  const float* bv   = (const float*)d_in[6];
  const float* wo   = (const float*)d_in[7];
  const float* bo   = (const float*)d_in[8];
  const float* nqw  = (const float*)d_in[9];
  const float* nkw  = (const float*)d_in[10];
  const float* fcos = (const float*)d_in[11];
  const float* fsin = (const float*)d_in[12];

  const size_t NEED = 125304832;
  if (ws_size < NEED) return;
  char* ws = (char*)d_ws;
  u16* x_bf   = (u16*)(ws + 0);            // dead after gemm_qkv; ml reuses
  u16* wq_bf  = (u16*)(ws + 13107200);
  u16* wk_bf  = (u16*)(ws + 21495808);
  u16* wv_bf  = (u16*)(ws + 29884416);
  u16* wo_bf  = (u16*)(ws + 38273024);
  float* preq = (float*)(ws + 46661632);   // dead after rms_rope(q)
  float* prek = (float*)(ws + 72876032);   // dead after rms_rope(k)
  u16* v_bf   = (u16*)(ws + 99090432);     // dead after transpose
  u16* q_bf   = (u16*)(ws + 112197632);
  u16* k_bf   = (u16*)(ws + 46661632);     // aliases preq (dead)
  u16* vT     = (u16*)(ws + 59768832);     // aliases preq tail; [2048][3200] pi-permuted
  u16* opart  = (u16*)(ws + 72876032);     // aliases prek (dead)
  float* ml   = (float*)(ws + 0);          // aliases x_bf (dead)
  u16* att_bf = (u16*)(ws + 99090432);     // aliases v_bf (dead)

  cast_all<<<11392, 256, 0, stream>>>(x, wq, wk, wv, wo, x_bf, wq_bf, wk_bf, wv_bf,
                                      wo_bf);

  const float foldq = 1.4426950408889634f * 0.08838834764831843f;  // log2e / sqrt(128)

  gemm_qkv<<<dim3(25, 48), 256, 0, stream>>>(x_bf, wq_bf, wk_bf, wv_bf, bq, bk, bv,
                                             preq, prek, v_bf);
  rms_rope<<<3200, 256, 0, stream>>>(preq, nqw, fcos, fsin, q_bf, foldq);
  rms_rope<<<3200, 256, 0, stream>>>(prek, nkw, fcos, fsin, k_bf, 1.0f);
  transpose_2d<<<dim3(50, 32), 256, 0, stream>>>(v_bf, vT);
  attn_kernel<<<dim3(50, 16, 2), 256, 0, stream>>>(q_bf, k_bf, vT, opart, ml);
  attn_combine<<<3200, 256, 0, stream>>>(opart, ml, att_bf);
  gemm_nt<0><<<dim3(25, 16), 256, 0, stream>>>(att_bf, wo_bf, bo, d_out);
}